// Round 1
// baseline (170.969 us; speedup 1.0000x reference)
//
#include <hip/hip_runtime.h>
#include <stdint.h>

#define NB 4      // batch
#define SEQ 1024  // sequence
#define DM 256    // d_model == head_dim
#define NH 8      // heads

typedef __attribute__((ext_vector_type(8))) short bf8;   // 8 bf16 (4 VGPRs)
typedef __attribute__((ext_vector_type(4))) float f4;    // MFMA accumulator

__device__ __forceinline__ unsigned short f2bf(float f) {
  union { float f; uint32_t u; } c; c.f = f;
  uint32_t u = c.u;
  return (unsigned short)((u + 0x7FFFu + ((u >> 16) & 1u)) >> 16); // RNE
}

// async global->LDS DMA, 16B per lane (m97 recipe): lds dst = base + lane*16.
__device__ __forceinline__ void gl_lds16(const unsigned short* g, short* l) {
  __builtin_amdgcn_global_load_lds(
      (const __attribute__((address_space(1))) unsigned int*)g,
      (__attribute__((address_space(3))) unsigned int*)l, 16, 0, 0);
}

// Fragment-major layouts (per bh slice = 262144 elems = 512 KB):
//  q_frag/k_frag: [tile16 (token/16)][dchunk (d/32)][lane64][j8]
//  v_frag:        [dtile (d/16)][kvchunk (kv/32)][lane64][j8]

// ---------------------------------------------------------------------------
// Kernel 0: ALL prep in one launch.  grid (1024, 7), 256 thr.  (unchanged)
// ---------------------------------------------------------------------------
__global__ __launch_bounds__(256) void prep_kernel(
    const float* __restrict__ Wq, const float* __restrict__ Wk,
    const float* __restrict__ Wv, const float* __restrict__ Wo,
    const float* __restrict__ Q, const float* __restrict__ K,
    const float* __restrict__ V,
    unsigned short* __restrict__ Wt3, unsigned short* __restrict__ WoT,
    unsigned short* __restrict__ Xbf) {
  const int z = blockIdx.y;
  const int tid = threadIdx.x;
  if (z >= 4) {
    const float* src = (z == 4) ? Q : (z == 5) ? K : V;
    const size_t off = (size_t)blockIdx.x * 1024 + tid * 4;
    const float4 v = *(const float4*)(src + off);
    short4 s;
    s.x = (short)f2bf(v.x); s.y = (short)f2bf(v.y);
    s.z = (short)f2bf(v.z); s.w = (short)f2bf(v.w);
    *(short4*)(Xbf + (size_t)(z - 4) * 4096 * 256 + off) = s;
    return;
  }
  if (blockIdx.x >= 512) return;
  const float* in;
  unsigned short* out;
  int R, C, bx, by;
  if (z < 3) {
    in = (z == 0) ? Wq : (z == 1) ? Wk : Wv;
    out = Wt3 + (size_t)z * 2048 * 256;
    R = 256; C = 2048; bx = blockIdx.x & 63; by = blockIdx.x >> 6;
  } else {
    in = Wo; out = WoT;
    R = 2048; C = 256; bx = blockIdx.x & 7; by = blockIdx.x >> 3;
  }
  __shared__ float t[32][33];
  const int c0 = bx * 32, r0 = by * 32;
  const int tx = tid & 31, ty = tid >> 5;
#pragma unroll
  for (int i = 0; i < 4; i++) {
    int r = r0 + ty + i * 8;
    t[ty + i * 8][tx] = in[(size_t)r * C + c0 + tx];
  }
  __syncthreads();
#pragma unroll
  for (int i = 0; i < 4; i++) {
    int c = c0 + ty + i * 8;
    out[(size_t)c * R + r0 + tx] = f2bf(t[tx][ty + i * 8]);
  }
}

// ---------------------------------------------------------------------------
// Kernel 1: QKV projection GEMM (unchanged)
// ---------------------------------------------------------------------------
__global__ __launch_bounds__(256) void proj_kernel(
    const unsigned short* __restrict__ Xbf, const unsigned short* __restrict__ Wt3,
    const float* __restrict__ bq, const float* __restrict__ bk, const float* __restrict__ bv,
    unsigned short* __restrict__ q_frag, unsigned short* __restrict__ k_frag,
    unsigned short* __restrict__ v_frag) {
  const int z = blockIdx.z;
  const unsigned short* X = Xbf + (size_t)z * 4096 * 256;
  const unsigned short* Wt = Wt3 + (size_t)z * 2048 * 256;
  const float* bias = (z == 0) ? bq : (z == 1) ? bk : bv;

  __shared__ short a_lds[128 * 32];
  __shared__ short b_lds[128 * 32];

  const int tid = threadIdx.x;
  const int wid = tid >> 6, lane = tid & 63;
  const int quad = lane >> 4, l16 = lane & 15;
  const int wm = wid >> 1, wn = wid & 1;
  const int m0 = blockIdx.x * 128, n0 = blockIdx.y * 128;

  f4 acc[4][4];
  const f4 z4 = {0.f, 0.f, 0.f, 0.f};
#pragma unroll
  for (int i = 0; i < 4; i++)
#pragma unroll
    for (int j = 0; j < 4; j++) acc[i][j] = z4;

  const int srow = lane >> 2;
  const int schunk = lane & 3;
  const int cxor = quad ^ (l16 & 3);

  for (int ko = 0; ko < 8; ko++) {
    const int k0 = ko * 32;
#pragma unroll
    for (int j = 0; j < 2; j++) {
      const int i = wid * 2 + j;
      const int row = i * 16 + srow;
      const int sc = (schunk ^ (row & 3)) * 8;
      gl_lds16(X + (size_t)(m0 + row) * DM + k0 + sc, a_lds + i * 512);
      gl_lds16(Wt + (size_t)(n0 + row) * DM + k0 + sc, b_lds + i * 512);
    }
    __syncthreads();
    bf8 af[4], bfv[4];
#pragma unroll
    for (int mi = 0; mi < 4; mi++)
      af[mi] = *(const bf8*)(a_lds + (wm * 64 + mi * 16 + l16) * 32 + cxor * 8);
#pragma unroll
    for (int ni = 0; ni < 4; ni++)
      bfv[ni] = *(const bf8*)(b_lds + (wn * 64 + ni * 16 + l16) * 32 + cxor * 8);
    if (z < 2) {
#pragma unroll
      for (int ni = 0; ni < 4; ni++)
#pragma unroll
        for (int mi = 0; mi < 4; mi++)
          acc[ni][mi] = __builtin_amdgcn_mfma_f32_16x16x32_bf16(bfv[ni], af[mi], acc[ni][mi], 0, 0, 0);
    } else {
#pragma unroll
      for (int mi = 0; mi < 4; mi++)
#pragma unroll
        for (int ni = 0; ni < 4; ni++)
          acc[mi][ni] = __builtin_amdgcn_mfma_f32_16x16x32_bf16(af[mi], bfv[ni], acc[mi][ni], 0, 0, 0);
    }
    __syncthreads();
  }

  if (z < 2) {
    // q scale folds 1/sqrt(256) AND log2(e) (softmax uses exp2 directly)
    const float scale = (z == 0) ? 0.0901684400f : 1.0f;
    unsigned short* dst = (z == 0) ? q_frag : k_frag;
#pragma unroll
    for (int ni = 0; ni < 4; ni++) {
      const int nb = n0 + wn * 64 + ni * 16 + quad * 4;  // 4 consecutive d
      const float4 b4 = *(const float4*)(bias + nb);
      const int h = nb >> 8, dd = nb & 255;
      const int dq = (dd >> 3) & 3, jh = dd & 7;
#pragma unroll
      for (int mi = 0; mi < 4; mi++) {
        const int tok = m0 + wm * 64 + mi * 16 + l16;
        const int b = tok >> 10, sr = tok & 1023;
        const size_t idx = ((size_t)(b * NH + h) * 64 + (sr >> 4)) * 4096 +
                           (size_t)(dd >> 5) * 512 + ((sr & 15) + 16 * dq) * 8 + jh;
        short4 s4;
        s4.x = (short)f2bf((acc[ni][mi][0] + b4.x) * scale);
        s4.y = (short)f2bf((acc[ni][mi][1] + b4.y) * scale);
        s4.z = (short)f2bf((acc[ni][mi][2] + b4.z) * scale);
        s4.w = (short)f2bf((acc[ni][mi][3] + b4.w) * scale);
        *(short4*)(dst + idx) = s4;
      }
    }
  } else {
#pragma unroll
    for (int ni = 0; ni < 4; ni++) {
      const int n = n0 + wn * 64 + ni * 16 + l16;
      const float bsv = bias[n];
      const int h = n >> 8, d = n & 255;
#pragma unroll
      for (int mi = 0; mi < 4; mi++) {
        const int m = m0 + wm * 64 + mi * 16 + quad * 4;
        const int b = m >> 10, sr = m & 1023;
        const size_t idx = ((size_t)(b * NH + h) * 16 + (d >> 4)) * 16384 +
                           (size_t)(sr >> 5) * 512 +
                           ((d & 15) + 16 * ((sr >> 3) & 3)) * 8 + (sr & 7);
        short4 s4;
        s4.x = (short)f2bf(acc[mi][ni][0] + bsv);
        s4.y = (short)f2bf(acc[mi][ni][1] + bsv);
        s4.z = (short)f2bf(acc[mi][ni][2] + bsv);
        s4.w = (short)f2bf(acc[mi][ni][3] + bsv);
        *(short4*)(v_frag + idx) = s4;
      }
    }
  }
}

// ---------------------------------------------------------------------------
// Kernel 2: flash attention v13.  kv-step = 64; waves are (wq,wk) quadrants of
// the 64q x 64kv step tile, so each wave owns 32 q-rows: K-LDS bytes per MFMA
// halve vs v12 (wave read whole 16KB K-tile for only 16 MFMAs).  Per CU per
// 64 kv: LDS reads 320KB -> 192KB.  4 independent 8-deep S-MFMA chains.
// K in 3x16KB buffers: sub0 (kv 0-31 of step) double-buffered, prefetched at
// step top; sub1 single-buffered, DMA'd after mid-step barrier (overlaps
// PV+softmax).  Barrier rate unchanged (2 per 64 kv).  P in split-padded
// [2][2][64][40] (v12's proven stride-40 bank pattern).  LDS 70,144 B ->
// still 2 blocks/CU.  vpre single-buffered (V(t) issued after PV(t-1)
// consumes it; ~softmax+barrier+S of hiding before use).
// ---------------------------------------------------------------------------
__global__ __launch_bounds__(256, 2) void attn_kernel(
    const unsigned short* __restrict__ q_frag, const unsigned short* __restrict__ k_frag,
    const unsigned short* __restrict__ v_frag, unsigned short* __restrict__ o_ws) {
  __shared__ short k_lds[3 * 8192];        // [0],[1]: sub0 dbuf; [2]: sub1
  __shared__ short p_lds[2][2][64][40];    // [dbuf][kv-half][q][kv-within-half]
  __shared__ float l_sh[2][64];            // [wk][q] partial row-sums

  const int tid = threadIdx.x;
  const int wid = tid >> 6, lane = tid & 63;
  const int quad = lane >> 4, l16 = lane & 15;
  const int wq = wid >> 1, wk = wid & 1;   // q-half, kv-half of the step tile
  const int blk = blockIdx.x;
  const int g = blk & 7;                 // XCD (dispatch round-robin heuristic)
  const int qt = (blk >> 3) & 15;        // q tile (64 rows)
  const int bh = g + 8 * (blk >> 7);     // 16 same-bh blocks share one XCD
  const size_t fbase = (size_t)bh * 262144;

  // prologue DMA first: K sub0(0) -> buf0, sub1(0) -> buf2
  const unsigned short* ksrc = k_frag + fbase + (size_t)wid * 2048 + lane * 8;
#pragma unroll
  for (int jj = 0; jj < 4; jj++) {
    gl_lds16(ksrc + jj * 512, &k_lds[wid * 2048 + jj * 512]);
    gl_lds16(ksrc + 8192 + jj * 512, &k_lds[2 * 8192 + wid * 2048 + jj * 512]);
  }

  // Q fragments: wave's own 32 q-rows (2 x 16-row subtiles), all 8 d-chunks.
  bf8 qf[2][8];
#pragma unroll
  for (int qi = 0; qi < 2; qi++) {
    const unsigned short* qp =
        q_frag + fbase + (size_t)(qt * 4 + wq * 2 + qi) * 4096 + lane * 8;
#pragma unroll
    for (int c = 0; c < 8; c++) qf[qi][c] = *(const bf8*)(qp + c * 512);
  }

  const f4 z4 = {0.f, 0.f, 0.f, 0.f};
  f4 Oacc[4][4];  // [mi(d)][nq(q)]: d = wid*64+mi*16+quad*4+reg, q = nq*16+l16
#pragma unroll
  for (int i = 0; i < 4; i++)
#pragma unroll
    for (int j = 0; j < 4; j++) Oacc[i][j] = z4;
  float lpart[2][4] = {{0.f, 0.f, 0.f, 0.f}, {0.f, 0.f, 0.f, 0.f}};

  __syncthreads();  // K(0) staged

  bf8 vpre[8];  // wave's 64-d slice x 64 kv of V(t); single-buffered
  const unsigned short* vsrc = v_frag + fbase + (size_t)(wid * 4) * 16384 + lane * 8;

  for (int t = 0; t < 16; t++) {
    const int cur = t & 1;
    // 1. prefetch DMA: sub0(t+1) -> other sub0 buffer (overlaps whole step)
    if (t < 15) {
      const unsigned short* s0 = ksrc + (size_t)(t + 1) * 16384;
#pragma unroll
      for (int jj = 0; jj < 4; jj++)
        gl_lds16(s0 + jj * 512, &k_lds[(cur ^ 1) * 8192 + wid * 2048 + jj * 512]);
    }
    // 2. S = Q_wq . K_wk^T : 32q x 32kv via 4 interleaved 8-deep chains
    const short* kb_base = &k_lds[(wk ? 2 : cur) * 8192];
    f4 S00 = z4, S01 = z4, S10 = z4, S11 = z4;
#pragma unroll
    for (int c = 0; c < 8; c++) {
      const bf8 kb0 = *(const bf8*)(kb_base + c * 512 + lane * 8);
      const bf8 kb1 = *(const bf8*)(kb_base + 4096 + c * 512 + lane * 8);
      S00 = __builtin_amdgcn_mfma_f32_16x16x32_bf16(qf[0][c], kb0, S00, 0, 0, 0);
      S01 = __builtin_amdgcn_mfma_f32_16x16x32_bf16(qf[0][c], kb1, S01, 0, 0, 0);
      S10 = __builtin_amdgcn_mfma_f32_16x16x32_bf16(qf[1][c], kb0, S10, 0, 0, 0);
      S11 = __builtin_amdgcn_mfma_f32_16x16x32_bf16(qf[1][c], kb1, S11, 0, 0, 0);
    }
    __syncthreads();  // sub1 readers done -> safe to overwrite buf2
    // 3. DMA sub1(t+1) -> buf2 (drains at step-end barrier; overlap PV+softmax)
    if (t < 15) {
      const unsigned short* s1 = ksrc + (size_t)(t + 1) * 16384 + 8192;
#pragma unroll
      for (int jj = 0; jj < 4; jj++)
        gl_lds16(s1 + jj * 512, &k_lds[2 * 8192 + wid * 2048 + jj * 512]);
    }
    // 4. PV(t-1): O += V(t-1)^T . P(t-1) over 64 kv
    if (t > 0) {
      const int prv = cur ^ 1;
#pragma unroll
      for (int ks = 0; ks < 2; ks++) {
        bf8 pb[4];
#pragma unroll
        for (int nq = 0; nq < 4; nq++)
          pb[nq] = *(const bf8*)(&p_lds[prv][ks][nq * 16 + l16][quad * 8]);
#pragma unroll
        for (int mi = 0; mi < 4; mi++)
#pragma unroll
          for (int nq = 0; nq < 4; nq++)
            Oacc[mi][nq] = __builtin_amdgcn_mfma_f32_16x16x32_bf16(
                vpre[ks * 4 + mi], pb[nq], Oacc[mi][nq], 0, 0, 0);
      }
    }
    // 5. V(t) loads (vpre free now; consumed next step / drain)
#pragma unroll
    for (int ks = 0; ks < 2; ks++)
#pragma unroll
      for (int mi = 0; mi < 4; mi++)
        vpre[ks * 4 + mi] =
            *(const bf8*)(vsrc + (size_t)mi * 16384 + (size_t)(2 * t + ks) * 512);
    // 6. softmax of the wave's 32q x 64kv quadrant -> p_lds[cur][wk]
#pragma unroll
    for (int reg = 0; reg < 4; reg++) {
      {
        const int qrow = wq * 32 + quad * 4 + reg;
        const float p0 = exp2f(S00[reg]);
        const float p1 = exp2f(S01[reg]);
        lpart[0][reg] += p0 + p1;
        union { float f; uint32_t u; } c0, c1;
        c0.f = p0; c1.f = p1;
        p_lds[cur][wk][qrow][l16] = (short)((c0.u + 0x8000u) >> 16);
        p_lds[cur][wk][qrow][16 + l16] = (short)((c1.u + 0x8000u) >> 16);
      }
      {
        const int qrow = wq * 32 + 16 + quad * 4 + reg;
        const float p0 = exp2f(S10[reg]);
        const float p1 = exp2f(S11[reg]);
        lpart[1][reg] += p0 + p1;
        union { float f; uint32_t u; } c0, c1;
        c0.f = p0; c1.f = p1;
        p_lds[cur][wk][qrow][l16] = (short)((c0.u + 0x8000u) >> 16);
        p_lds[cur][wk][qrow][16 + l16] = (short)((c1.u + 0x8000u) >> 16);
      }
    }
    __syncthreads();  // drains sub1 DMA; P(t) visible; flip buffers
  }

  // ---- drain: PV(15) from p_lds[1] + vpre = V(15)
  {
#pragma unroll
    for (int ks = 0; ks < 2; ks++) {
      bf8 pb[4];
#pragma unroll
      for (int nq = 0; nq < 4; nq++)
        pb[nq] = *(const bf8*)(&p_lds[1][ks][nq * 16 + l16][quad * 8]);
#pragma unroll
      for (int mi = 0; mi < 4; mi++)
#pragma unroll
        for (int nq = 0; nq < 4; nq++)
          Oacc[mi][nq] = __builtin_amdgcn_mfma_f32_16x16x32_bf16(
              vpre[ks * 4 + mi], pb[nq], Oacc[mi][nq], 0, 0, 0);
    }
  }

  // ---- final l: reduce over the wave's 16 kv-col lanes, publish per wk-half
#pragma unroll
  for (int qi = 0; qi < 2; qi++)
#pragma unroll
    for (int reg = 0; reg < 4; reg++) {
      float v = lpart[qi][reg];
      v += __shfl_xor(v, 1, 64);
      v += __shfl_xor(v, 2, 64);
      v += __shfl_xor(v, 4, 64);
      v += __shfl_xor(v, 8, 64);
      if (l16 == 0) l_sh[wk][wq * 32 + qi * 16 + quad * 4 + reg] = v;
    }
  __syncthreads();

  // ---- epilogue: O^T[d][q] / l(q) -> o_ws [B,S,H*256]
  const int b = bh >> 3, h = bh & 7;
#pragma unroll
  for (int nq = 0; nq < 4; nq++) {
    const int q = nq * 16 + l16;
    const float inv = 1.f / (l_sh[0][q] + l_sh[1][q]);
    const size_t base = ((size_t)b * SEQ + qt * 64 + q) * (NH * DM) + h * DM + wid * 64;
#pragma unroll
    for (int mi = 0; mi < 4; mi++) {
      short4 s4;
      s4.x = (short)f2bf(Oacc[mi][nq][0] * inv);
      s4.y = (short)f2bf(Oacc[mi][nq][1] * inv);
      s4.z = (short)f2bf(Oacc[mi][nq][2] * inv);
      s4.w = (short)f2bf(Oacc[mi][nq][3] * inv);
      *(short4*)(o_ws + base + mi * 16 + quad * 4) = s4;
    }
  }
}

// ---------------------------------------------------------------------------
// Kernel 3: output projection.  BM=32, BN=64, BK=128, grid (128,4).  (unchanged)
// ---------------------------------------------------------------------------
__global__ __launch_bounds__(256) void outproj_kernel(
    const unsigned short* __restrict__ o_ws, const unsigned short* __restrict__ WoT,
    const float* __restrict__ bo, float* __restrict__ out) {
  __shared__ short a_lds[32][136];
  __shared__ short b_lds[64][136];

  const int tid = threadIdx.x;
  const int wid = tid >> 6, lane = tid & 63;
  const int quad = lane >> 4, l16 = lane & 15;
  const int wm = wid & 1, wn = wid >> 1;
  const int m0 = blockIdx.x * 32, n0 = blockIdx.y * 64;

  const f4 z4 = {0.f, 0.f, 0.f, 0.f};
  f4 acc[2];
#pragma unroll
  for (int i = 0; i < 2; i++) acc[i] = z4;

  const int ch = tid & 15, row = tid >> 4;
  for (int ko = 0; ko < 16; ko++) {
    const int k0 = ko * 128;
#pragma unroll
    for (int rb = 0; rb < 2; rb++) {
      int r = row + rb * 16;
      *(bf8*)(&a_lds[r][ch * 8]) = *(const bf8*)(o_ws + (size_t)(m0 + r) * 2048 + k0 + ch * 8);
    }
#pragma unroll
    for (int rb = 0; rb < 4; rb++) {
      int r = row + rb * 16;
      *(bf8*)(&b_lds[r][ch * 8]) = *(const bf8*)(WoT + (size_t)(n0 + r) * 2048 + k0 + ch * 8);
    }
    __syncthreads();
#pragma unroll
    for (int kc = 0; kc < 4; kc++) {
      const bf8 af = *(const bf8*)(&a_lds[wm * 16 + l16][kc * 32 + quad * 8]);
      bf8 bfv[2];
#pragma unroll
      for (int ni = 0; ni < 2; ni++)
        bfv[ni] = *(const bf8*)(&b_lds[wn * 32 + ni * 16 + l16][kc * 32 + quad * 8]);
#pragma unroll
      for (int ni = 0; ni < 2; ni++)
        acc[ni] = __builtin_amdgcn_mfma_f32_16x16x32_bf16(af, bfv[ni], acc[ni], 0, 0, 0);
    }
    __syncthreads();
  }
#pragma unroll
  for (int ni = 0; ni < 2; ni++) {
    const int n = n0 + wn * 32 + ni * 16 + l16;
    const float bv = bo[n];
#pragma unroll
    for (int reg = 0; reg < 4; reg++) {
      const int m = m0 + wm * 16 + quad * 4 + reg;
      out[(size_t)m * DM + n] = acc[ni][reg] + bv;
    }
  }
}

// ---------------------------------------------------------------------------
extern "C" void kernel_launch(void* const* d_in, const int* in_sizes, int n_in,
                              void* d_out, int out_size, void* d_ws, size_t ws_size,
                              hipStream_t stream) {
  const float* Q  = (const float*)d_in[0];
  const float* K  = (const float*)d_in[1];
  const float* V  = (const float*)d_in[2];
  const float* Wq = (const float*)d_in[3];
  const float* bq = (const float*)d_in[4];
  const float* Wk = (const float*)d_in[5];
  const float* bk = (const float*)d_in[6];
  const float* Wv = (const float*)d_in[7];
  const float* bv = (const float*)d_in[8];
  const float* Wo = (const float*)d_in[9];
  const float* bo = (const float*)d_in[10];
  float* out = (float*)d_out;

  char* ws = (char*)d_ws;
  const size_t QS = (size_t)NB * NH * SEQ * DM * 2;  // 16 MiB each
  unsigned short* q_frag = (unsigned short*)(ws);
  unsigned short* k_frag = (unsigned short*)(ws + QS);
  unsigned short* v_frag = (unsigned short*)(ws + 2 * QS);
  unsigned short* o_ws   = (unsigned short*)(ws + 3 * QS);
  const size_t WT = (size_t)2048 * 256 * 2;  // 1 MiB each
  unsigned short* Wt3 = (unsigned short*)(ws + 4 * QS);           // 3 MiB
  unsigned short* WoT = (unsigned short*)(ws + 4 * QS + 3 * WT);  // 1 MiB
  // Xbf (6 MiB) aliases o_ws: proj reads it before attn overwrites o_ws.
  unsigned short* Xbf = o_ws;

  prep_kernel<<<dim3(1024, 7), 256, 0, stream>>>(Wq, Wk, Wv, Wo, Q, K, V,
                                                 Wt3, WoT, Xbf);
  proj_kernel<<<dim3(32, 16, 3), 256, 0, stream>>>(Xbf, Wt3, bq, bk, bv,
                                                   q_frag, k_frag, v_frag);
  attn_kernel<<<512, 256, 0, stream>>>(q_frag, k_frag, v_frag, o_ws);
  outproj_kernel<<<dim3(128, 4), 256, 0, stream>>>(o_ws, WoT, bo, out);
}